// Round 2
// baseline (1645.117 us; speedup 1.0000x reference)
//
#include <hip/hip_runtime.h>
#include <stdint.h>

// ---------------------------------------------------------------------------
// TransformerBlock: 3x (LN -> FC(768,3072) -> GELU -> FC(3072,N)) + attention.
// Inputs/outputs fp32 (per reference); internal compute bf16 with fp32 acc.
// GEMMs: m97-style MFMA structure (128x128 tile, BK=64, global_load_lds(16B),
// mfma_f32_16x16x32_bf16, verified layouts) + XOR swizzle on LDS 16B chunks
// to break ds_read_b128 bank conflicts of the naive [m][k] layout.
// Weights are fp32 K x N; pre-transposed+converted to bf16 N x K each call.
// Attention: S^T = scale*K.Q^T (batched GEMM, 24-head chunks aliasing the MLP
// hidden buffer), column softmax in place, out = P.Vt^T.
// ---------------------------------------------------------------------------

typedef unsigned short u16;
typedef __attribute__((ext_vector_type(8))) short bf16x8;
typedef __attribute__((ext_vector_type(4))) float f32x4;
typedef __attribute__((address_space(1))) unsigned int as1_u32;
typedef __attribute__((address_space(3))) unsigned int as3_u32;

__device__ __forceinline__ float bf2f(u16 u) {
  union { unsigned int i; float f; } v; v.i = ((unsigned int)u) << 16; return v.f;
}
__device__ __forceinline__ u16 f2bf(float f) {
  union { float f; unsigned int i; } v; v.f = f;
  unsigned int r = v.i + 0x7fffu + ((v.i >> 16) & 1u);  // RNE
  return (u16)(r >> 16);
}
__device__ __forceinline__ float gelu_exact(float x) {
  return 0.5f * x * (1.0f + erff(x * 0.70710678118654752f));
}
__device__ __forceinline__ void async_ld16(const u16* g, u16* l) {
  __builtin_amdgcn_global_load_lds((const as1_u32*)g, (as3_u32*)l, 16, 0, 0);
}

// ------------------- LayerNorm (per token, C=768) -> bf16 -------------------
// inF32: input rows are fp32; else bf16. gamma/beta fp32. Output bf16.
__global__ __launch_bounds__(256) void ln_kernel(const void* __restrict__ xv,
                                                 const float* __restrict__ g,
                                                 const float* __restrict__ be,
                                                 u16* __restrict__ out, int inF32) {
  int token = blockIdx.x, tid = threadIdx.x;
  float v0, v1, v2;
  if (inF32) {
    const float* row = (const float*)xv + (size_t)token * 768;
    v0 = row[tid]; v1 = row[tid + 256]; v2 = row[tid + 512];
  } else {
    const u16* row = (const u16*)xv + (size_t)token * 768;
    v0 = bf2f(row[tid]); v1 = bf2f(row[tid + 256]); v2 = bf2f(row[tid + 512]);
  }
  __shared__ float rs[256], rq[256];
  rs[tid] = v0 + v1 + v2;
  rq[tid] = v0 * v0 + v1 * v1 + v2 * v2;
  __syncthreads();
  for (int off = 128; off > 0; off >>= 1) {
    if (tid < off) { rs[tid] += rs[tid + off]; rq[tid] += rq[tid + off]; }
    __syncthreads();
  }
  float mean = rs[0] * (1.0f / 768.0f);
  float var  = rq[0] * (1.0f / 768.0f) - mean * mean;
  float inv  = rsqrtf(var + 1e-5f);
  u16* o = out + (size_t)token * 768;
  o[tid]       = f2bf((v0 - mean) * inv * g[tid]       + be[tid]);
  o[tid + 256] = f2bf((v1 - mean) * inv * g[tid + 256] + be[tid + 256]);
  o[tid + 512] = f2bf((v2 - mean) * inv * g[tid + 512] + be[tid + 512]);
}

// ------------- fp32 (R x C) -> bf16 transposed (C x R) ----------------------
__global__ __launch_bounds__(256) void transpose_f32_bf16(const float* __restrict__ in,
                                                          u16* __restrict__ out,
                                                          int R, int Cc) {
  __shared__ u16 tile[32][33];
  int c0 = blockIdx.x * 32, r0 = blockIdx.y * 32;
  int tx = threadIdx.x, ty = threadIdx.y;  // 32 x 8
  for (int i = ty; i < 32; i += 8)
    tile[i][tx] = f2bf(in[(size_t)(r0 + i) * Cc + c0 + tx]);
  __syncthreads();
  for (int i = ty; i < 32; i += 8)
    out[(size_t)(c0 + i) * R + r0 + tx] = tile[tx][i];
}

// ------------- V transpose: t(token, 1536 + h*64 + c) -> vt[bh][c][t] -------
__global__ __launch_bounds__(256) void vtrans(const u16* __restrict__ t,
                                              u16* __restrict__ vt) {
  int bh = blockIdx.z, b = bh / 12, h = bh % 12;
  int t0 = blockIdx.x * 32, c0 = blockIdx.y * 32;
  __shared__ u16 tile[32][33];
  int tx = threadIdx.x, ty = threadIdx.y;
  for (int i = ty; i < 32; i += 8)
    tile[i][tx] = t[(size_t)(b * 1024 + t0 + i) * 2304 + 1536 + h * 64 + c0 + tx];
  __syncthreads();
  for (int i = ty; i < 32; i += 8)
    vt[(size_t)bh * 65536 + (size_t)(c0 + i) * 1024 + t0 + tx] = tile[tx][i];
}

// ----------------------------- MFMA GEMM ------------------------------------
// C[m][n] = act(alpha * sum_k A[m][k]*Bt[n][k] + bias[n]); bf16 in, fp32 acc.
// cF32: C is float*, else bf16 (u16*).
// Per-z offsets: off = base + (bh/div)*p1 + (bh%div)*p2, bh = blockIdx.z+zBase.
#define BM 128
#define BN 128
#define BKK 64

__global__ __launch_bounds__(256, 2) void gemm_mfma(
    const u16* __restrict__ A, long long aBase, int aDiv, long long aP1, long long aP2, int lda,
    const u16* __restrict__ B, long long bBase, int bDiv, long long bP1, long long bP2, int ldb,
    void* __restrict__ C, long long cBase, int cDiv, long long cP1, long long cP2, int ldc,
    int M, int N, int K, int zBase,
    const float* __restrict__ bias, float alpha, int act, int cF32) {
  __shared__ u16 As[BM * BKK];
  __shared__ u16 Bs[BN * BKK];
  int bh = blockIdx.z + zBase;
  long long aOff = aBase + (long long)(bh / aDiv) * aP1 + (long long)(bh % aDiv) * aP2;
  long long bOff = bBase + (long long)(bh / bDiv) * bP1 + (long long)(bh % bDiv) * bP2;
  long long cOff = cBase + (long long)(bh / cDiv) * cP1 + (long long)(bh % cDiv) * cP2;
  int m0 = blockIdx.y * BM, n0 = blockIdx.x * BN;
  int tid = threadIdx.x;
  int wave = tid >> 6, lane = tid & 63;
  int quad = lane >> 4, lo = lane & 15;
  int wr = (wave >> 1) * 64, wc = (wave & 1) * 64;

  f32x4 acc[4][4];
#pragma unroll
  for (int i = 0; i < 4; ++i)
#pragma unroll
    for (int j = 0; j < 4; ++j) acc[i][j] = (f32x4){0.f, 0.f, 0.f, 0.f};

  const u16* Ap = A + aOff;
  const u16* Bp = B + bOff;

  for (int k0 = 0; k0 < K; k0 += BKK) {
    // Stage 128x64 bf16 tiles of A and Bt. global_load_lds: LDS dest is
    // wave-uniform base + lane*16B, so per-lane choice lives in the GLOBAL
    // address: lane (row, slot) fetches global 16B-chunk  slot ^ (row&7)
    // (XOR swizzle -> conflict-free ds_read_b128 fragment reads later).
#pragma unroll
    for (int p = 0; p < 4; ++p) {
      int idx = tid + p * 256;
      int row = idx >> 3;
      int gch = ((idx & 7) ^ (row & 7)) * 8;      // global k-chunk (elements)
      int ldsOff = (wave * 64 + p * 256) * 8;     // wave-uniform, u16 units
      int ar = m0 + row; ar = ar < M ? ar : M - 1;
      async_ld16(Ap + (long long)ar * lda + k0 + gch, As + ldsOff);
      int br = n0 + row; br = br < N ? br : N - 1;
      async_ld16(Bp + (long long)br * ldb + k0 + gch, Bs + ldsOff);
    }
    __syncthreads();
#pragma unroll
    for (int ks = 0; ks < 2; ++ks) {
      bf16x8 af[4], bf[4];
#pragma unroll
      for (int i = 0; i < 4; ++i) {
        int m = wr + i * 16 + lo;
        int slot = (ks * 4 + quad) ^ (m & 7);     // un-swizzle
        af[i] = *(const bf16x8*)(As + m * BKK + slot * 8);
      }
#pragma unroll
      for (int j = 0; j < 4; ++j) {
        int n = wc + j * 16 + lo;
        int slot = (ks * 4 + quad) ^ (n & 7);
        bf[j] = *(const bf16x8*)(Bs + n * BKK + slot * 8);
      }
#pragma unroll
      for (int i = 0; i < 4; ++i)
#pragma unroll
        for (int j = 0; j < 4; ++j)
          acc[i][j] = __builtin_amdgcn_mfma_f32_16x16x32_bf16(af[i], bf[j], acc[i][j], 0, 0, 0);
    }
    __syncthreads();
  }

  // Epilogue. C/D layout (verified m89/m91): col = lane&15, row = quad*4+reg.
#pragma unroll
  for (int j = 0; j < 4; ++j) {
    int col = n0 + wc + j * 16 + lo;
    if (col >= N) continue;
    float bv = bias ? bias[col] : 0.0f;
#pragma unroll
    for (int i = 0; i < 4; ++i) {
      int rb = m0 + wr + i * 16 + quad * 4;
#pragma unroll
      for (int r = 0; r < 4; ++r) {
        int row = rb + r;
        if (row >= M) continue;
        float v = acc[i][j][r] * alpha + bv;
        if (act) v = gelu_exact(v);
        long long ci = cOff + (long long)row * ldc + col;
        if (cF32) ((float*)C)[ci] = v;
        else      ((u16*)C)[ci] = f2bf(v);
      }
    }
  }
}

// ------------- column softmax of S^T slice (in place, per head) -------------
// S layout: [z][l][t], softmax over l for each t. grid (16, Z), block 256.
__global__ __launch_bounds__(256) void softmax_cols(u16* __restrict__ S) {
  int z = blockIdx.y;
  int t0 = blockIdx.x * 64;
  int tt = threadIdx.x & 63, part = threadIdx.x >> 6;
  u16* base = S + (size_t)z * 1048576 + t0 + tt;
  float m = -1e30f, s = 0.f;
  for (int l = part; l < 1024; l += 4) {
    float x = bf2f(base[(size_t)l * 1024]);
    if (x > m) { s = s * __expf(m - x) + 1.f; m = x; }
    else        s += __expf(x - m);
  }
  __shared__ float sm[4][64], ss[4][64];
  sm[part][tt] = m; ss[part][tt] = s;
  __syncthreads();
  if (part == 0) {
    float M2 = sm[0][tt], S2 = ss[0][tt];
    for (int q = 1; q < 4; ++q) {
      float mq = sm[q][tt], sq = ss[q][tt];
      if (mq > M2) { S2 = S2 * __expf(M2 - mq) + sq; M2 = mq; }
      else          S2 += sq * __expf(mq - M2);
    }
    sm[0][tt] = M2; ss[0][tt] = 1.0f / S2;
  }
  __syncthreads();
  float M2 = sm[0][tt], inv = ss[0][tt];
  for (int l = part; l < 1024; l += 4) {
    size_t off = (size_t)l * 1024;
    float x = bf2f(base[off]);
    base[off] = f2bf(__expf(x - M2) * inv);
  }
}

// ----------------------------- host orchestration ---------------------------
static void run_block(hipStream_t stream, const void* inp, int inF32,
                      const float* g, const float* be,
                      const float* W1, const float* b1, const float* W2, const float* b2,
                      int N2, void* outp, int outF32,
                      u16* xn, u16* hS, u16* wt1, u16* wt2) {
  transpose_f32_bf16<<<dim3(3072 / 32, 768 / 32), dim3(32, 8), 0, stream>>>(W1, wt1, 768, 3072);
  transpose_f32_bf16<<<dim3(N2 / 32, 3072 / 32), dim3(32, 8), 0, stream>>>(W2, wt2, 3072, N2);
  ln_kernel<<<8192, 256, 0, stream>>>(inp, g, be, xn, inF32);
  gemm_mfma<<<dim3(3072 / 128, 8192 / 128, 1), dim3(256), 0, stream>>>(
      xn,  0, 1, 0, 0, 768,
      wt1, 0, 1, 0, 0, 768,
      hS,  0, 1, 0, 0, 3072,
      8192, 3072, 768, 0, b1, 1.0f, 1, 0);
  gemm_mfma<<<dim3(N2 / 128, 8192 / 128, 1), dim3(256), 0, stream>>>(
      hS,  0, 1, 0, 0, 3072,
      wt2, 0, 1, 0, 0, 3072,
      outp, 0, 1, 0, 0, N2,
      8192, N2, 3072, 0, b2, 1.0f, 0, outF32);
}

extern "C" void kernel_launch(void* const* d_in, const int* in_sizes, int n_in,
                              void* d_out, int out_size, void* d_ws, size_t ws_size,
                              hipStream_t stream) {
  const float* x       = (const float*)d_in[0];
  const float* qkv_g   = (const float*)d_in[1];
  const float* qkv_b   = (const float*)d_in[2];
  const float* qkv_W1  = (const float*)d_in[3];
  const float* qkv_b1  = (const float*)d_in[4];
  const float* qkv_W2  = (const float*)d_in[5];
  const float* qkv_b2  = (const float*)d_in[6];
  const float* proj_g  = (const float*)d_in[7];
  const float* proj_b  = (const float*)d_in[8];
  const float* proj_W1 = (const float*)d_in[9];
  const float* proj_b1 = (const float*)d_in[10];
  const float* proj_W2 = (const float*)d_in[11];
  const float* proj_b2 = (const float*)d_in[12];
  const float* mlp_g   = (const float*)d_in[13];
  const float* mlp_b   = (const float*)d_in[14];
  const float* mlp_W1  = (const float*)d_in[15];
  const float* mlp_b1  = (const float*)d_in[16];
  const float* mlp_W2  = (const float*)d_in[17];
  const float* mlp_b2  = (const float*)d_in[18];

  u16* ws  = (u16*)d_ws;               // element offsets (u16), ~157 MB total
  u16* xn  = ws;                       //  6291456  (LN output, 8192x768, bf16)
  u16* tb  = ws + 6291456;             // 18874368  (qkv out, 8192x2304)
  u16* ao  = ws + 25165824;            //  6291456  (attention out)
  u16* yb  = ws + 31457280;            //  6291456  (proj block out)
  u16* vt  = ws + 37748736;            //  6291456  (V transposed, [96][64][1024])
  u16* wt1 = ws + 44040192;            //  2359296  (W1^T bf16, per-block reuse)
  u16* wt2 = ws + 46399488;            //  7077888  (W2^T bf16, per-block reuse)
  u16* hS  = ws + 53477376;            // 25165824  (hidden 8192x3072 ALIASES S chunk 24x1024x1024)

  // ---- qkv block ----
  run_block(stream, x, 1, qkv_g, qkv_b, qkv_W1, qkv_b1, qkv_W2, qkv_b2, 2304,
            tb, 0, xn, hS, wt1, wt2);

  // ---- attention ----
  vtrans<<<dim3(32, 2, 96), dim3(32, 8), 0, stream>>>(tb, vt);
  for (int c = 0; c < 4; ++c) {
    int zb = c * 24;
    // S^T[l][t] = 0.125 * sum_c K[l][c] * Q[t][c]   (per head, 24-head chunk)
    gemm_mfma<<<dim3(8, 8, 24), dim3(256), 0, stream>>>(
        tb, 768LL, 12, 2359296LL, 64LL, 2304,        // A = K rows (k-contig)
        tb, 0LL,   12, 2359296LL, 64LL, 2304,        // Bt = Q rows (k-contig)
        hS, -(long long)zb * 1048576LL, 1, 1048576LL, 0LL, 1024,
        1024, 1024, 64, zb, nullptr, 0.125f, 0, 0);
    softmax_cols<<<dim3(16, 24), dim3(256), 0, stream>>>(hS);
    // out[l][c] = sum_t P[l][t] * Vt[c][t] -> ao[(b*1024+l)*768 + h*64 + c]
    gemm_mfma<<<dim3(1, 8, 24), dim3(256), 0, stream>>>(
        hS, -(long long)zb * 1048576LL, 1, 1048576LL, 0LL, 1024,
        vt, 0LL, 1, 65536LL, 0LL, 1024,
        ao, 0LL, 12, 786432LL, 64LL, 768,
        1024, 64, 1024, zb, nullptr, 1.0f, 0, 0);
  }

  // ---- proj block ----
  run_block(stream, ao, 0, proj_g, proj_b, proj_W1, proj_b1, proj_W2, proj_b2, 768,
            yb, 0, xn, hS, wt1, wt2);
  // ---- mlp block ----
  run_block(stream, yb, 0, mlp_g, mlp_b, mlp_W1, mlp_b1, mlp_W2, mlp_b2, 768,
            d_out, 1, xn, hS, wt1, wt2);
}

// Round 3
// 733.078 us; speedup vs baseline: 2.2441x; 2.2441x over previous
//
#include <hip/hip_runtime.h>
#include <stdint.h>

// ---------------------------------------------------------------------------
// TransformerBlock: 3x (LN -> FC(768,3072) -> GELU -> FC(3072,N)) + attention.
// fp32 in/out, bf16 MFMA compute with fp32 acc.
// Round-2: fused attention. Softmax axis (l) != PV contraction axis (t), so
//   out[l][c] = sum_t exp(S[l][t]) * invZ[t] * V[t][c],  Z[t]=sum_l exp(S[l][t])
// -> zstats kernel computes invZ (MFMA QK + column reduce), attn_out recomputes
// QK tiles, applies exp*invZ in-register, LDS round-trip (wave-local) to
// A-layout, MFMA vs V^T. S (201 MB) never materialized; softmax passes gone.
// ---------------------------------------------------------------------------

typedef unsigned short u16;
typedef __attribute__((ext_vector_type(8))) short bf16x8;
typedef __attribute__((ext_vector_type(4))) float f32x4;
typedef __attribute__((address_space(1))) unsigned int as1_u32;
typedef __attribute__((address_space(3))) unsigned int as3_u32;

__device__ __forceinline__ float bf2f(u16 u) {
  union { unsigned int i; float f; } v; v.i = ((unsigned int)u) << 16; return v.f;
}
__device__ __forceinline__ u16 f2bf(float f) {
  union { float f; unsigned int i; } v; v.f = f;
  unsigned int r = v.i + 0x7fffu + ((v.i >> 16) & 1u);  // RNE
  return (u16)(r >> 16);
}
__device__ __forceinline__ float gelu_exact(float x) {
  return 0.5f * x * (1.0f + erff(x * 0.70710678118654752f));
}
__device__ __forceinline__ void async_ld16(const u16* g, u16* l) {
  __builtin_amdgcn_global_load_lds((const as1_u32*)g, (as3_u32*)l, 16, 0, 0);
}

// ------------------- LayerNorm (per token, C=768) -> bf16 -------------------
__global__ __launch_bounds__(256) void ln_kernel(const void* __restrict__ xv,
                                                 const float* __restrict__ g,
                                                 const float* __restrict__ be,
                                                 u16* __restrict__ out, int inF32) {
  int token = blockIdx.x, tid = threadIdx.x;
  int wave = tid >> 6, lane = tid & 63;
  float v0, v1, v2;
  if (inF32) {
    const float* row = (const float*)xv + (size_t)token * 768;
    v0 = row[tid]; v1 = row[tid + 256]; v2 = row[tid + 512];
  } else {
    const u16* row = (const u16*)xv + (size_t)token * 768;
    v0 = bf2f(row[tid]); v1 = bf2f(row[tid + 256]); v2 = bf2f(row[tid + 512]);
  }
  float s = v0 + v1 + v2;
  float q = v0 * v0 + v1 * v1 + v2 * v2;
#pragma unroll
  for (int m = 1; m < 64; m <<= 1) { s += __shfl_xor(s, m); q += __shfl_xor(q, m); }
  __shared__ float red[8];
  if (lane == 0) { red[wave] = s; red[4 + wave] = q; }
  __syncthreads();
  s = red[0] + red[1] + red[2] + red[3];
  q = red[4] + red[5] + red[6] + red[7];
  float mean = s * (1.0f / 768.0f);
  float var  = q * (1.0f / 768.0f) - mean * mean;
  float inv  = rsqrtf(var + 1e-5f);
  u16* o = out + (size_t)token * 768;
  o[tid]       = f2bf((v0 - mean) * inv * g[tid]       + be[tid]);
  o[tid + 256] = f2bf((v1 - mean) * inv * g[tid + 256] + be[tid + 256]);
  o[tid + 512] = f2bf((v2 - mean) * inv * g[tid + 512] + be[tid + 512]);
}

// ------------- fp32 (R x C) -> bf16 transposed (C x R) ----------------------
__global__ __launch_bounds__(256) void transpose_f32_bf16(const float* __restrict__ in,
                                                          u16* __restrict__ out,
                                                          int R, int Cc) {
  __shared__ u16 tile[32][33];
  int c0 = blockIdx.x * 32, r0 = blockIdx.y * 32;
  int tx = threadIdx.x, ty = threadIdx.y;  // 32 x 8
  for (int i = ty; i < 32; i += 8)
    tile[i][tx] = f2bf(in[(size_t)(r0 + i) * Cc + c0 + tx]);
  __syncthreads();
  for (int i = ty; i < 32; i += 8)
    out[(size_t)(c0 + i) * R + r0 + tx] = tile[tx][i];
}

// ------------- V transpose: t(token, 1536 + h*64 + c) -> vt[bh][c][t] -------
__global__ __launch_bounds__(256) void vtrans(const u16* __restrict__ t,
                                              u16* __restrict__ vt) {
  int bh = blockIdx.z, b = bh / 12, h = bh % 12;
  int t0 = blockIdx.x * 32, c0 = blockIdx.y * 32;
  __shared__ u16 tile[32][33];
  int tx = threadIdx.x, ty = threadIdx.y;
  for (int i = ty; i < 32; i += 8)
    tile[i][tx] = t[(size_t)(b * 1024 + t0 + i) * 2304 + 1536 + h * 64 + c0 + tx];
  __syncthreads();
  for (int i = ty; i < 32; i += 8)
    vt[(size_t)bh * 65536 + (size_t)(c0 + i) * 1024 + t0 + tx] = tile[tx][i];
}

// ----------------------------- MFMA GEMM (FC layers) ------------------------
#define BM 128
#define BN 128
#define BKK 64

__global__ __launch_bounds__(256, 4) void gemm_mfma(
    const u16* __restrict__ A, int lda,
    const u16* __restrict__ B, int ldb,
    void* __restrict__ C, int ldc,
    int M, int N, int K,
    const float* __restrict__ bias, int act, int cF32) {
  __shared__ u16 As[BM * BKK];
  __shared__ u16 Bs[BN * BKK];
  int m0 = blockIdx.y * BM, n0 = blockIdx.x * BN;
  int tid = threadIdx.x;
  int wave = tid >> 6, lane = tid & 63;
  int quad = lane >> 4, lo = lane & 15;
  int wr = (wave >> 1) * 64, wc = (wave & 1) * 64;

  f32x4 acc[4][4];
#pragma unroll
  for (int i = 0; i < 4; ++i)
#pragma unroll
    for (int j = 0; j < 4; ++j) acc[i][j] = (f32x4){0.f, 0.f, 0.f, 0.f};

  for (int k0 = 0; k0 < K; k0 += BKK) {
    // XOR-swizzled staging: lane(row,slot) fetches global chunk slot^(row&7)
#pragma unroll
    for (int p = 0; p < 4; ++p) {
      int idx = tid + p * 256;
      int row = idx >> 3;
      int gch = ((idx & 7) ^ (row & 7)) * 8;
      int ldsOff = (wave * 64 + p * 256) * 8;
      async_ld16(A + (long long)(m0 + row) * lda + k0 + gch, As + ldsOff);
      async_ld16(B + (long long)(n0 + row) * ldb + k0 + gch, Bs + ldsOff);
    }
    __syncthreads();
#pragma unroll
    for (int ks = 0; ks < 2; ++ks) {
      bf16x8 af[4], bf[4];
#pragma unroll
      for (int i = 0; i < 4; ++i) {
        int m = wr + i * 16 + lo;
        int slot = (ks * 4 + quad) ^ (m & 7);
        af[i] = *(const bf16x8*)(As + m * BKK + slot * 8);
      }
#pragma unroll
      for (int j = 0; j < 4; ++j) {
        int n = wc + j * 16 + lo;
        int slot = (ks * 4 + quad) ^ (n & 7);
        bf[j] = *(const bf16x8*)(Bs + n * BKK + slot * 8);
      }
#pragma unroll
      for (int i = 0; i < 4; ++i)
#pragma unroll
        for (int j = 0; j < 4; ++j)
          acc[i][j] = __builtin_amdgcn_mfma_f32_16x16x32_bf16(af[i], bf[j], acc[i][j], 0, 0, 0);
    }
    __syncthreads();
  }

  // C/D layout: col = lane&15, row = quad*4+reg.
#pragma unroll
  for (int j = 0; j < 4; ++j) {
    int col = n0 + wc + j * 16 + lo;
    float bv = bias ? bias[col] : 0.0f;
#pragma unroll
    for (int i = 0; i < 4; ++i) {
      int rb = m0 + wr + i * 16 + quad * 4;
#pragma unroll
      for (int r = 0; r < 4; ++r) {
        int row = rb + r;
        float v = acc[i][j][r] + bv;
        if (act) v = gelu_exact(v);
        long long ci = (long long)row * ldc + col;
        if (cF32) ((float*)C)[ci] = v;
        else      ((u16*)C)[ci] = f2bf(v);
      }
    }
  }
}

// --------------- zstats: invZ[t] = 1 / sum_l exp(0.125*K[l].Q[t]) -----------
// grid (8 t-blocks, 96 bh), block 256. tb holds qkv output rows of 2304.
__global__ __launch_bounds__(256, 2) void zstats(const u16* __restrict__ tb,
                                                 float* __restrict__ zinv) {
  int bh = blockIdx.y, b = bh / 12, h = bh % 12;
  int t0 = blockIdx.x * 128;
  __shared__ u16 Qs[128 * 64];
  __shared__ u16 Ks[128 * 64];
  __shared__ float zred[4][128];
  int tid = threadIdx.x, wave = tid >> 6, lane = tid & 63;
  int quad = lane >> 4, lo = lane & 15;
  const u16* qbase = tb + (size_t)(b * 1024) * 2304 + h * 64;
  const u16* kbase = qbase + 768;

#pragma unroll
  for (int p = 0; p < 4; ++p) {
    int idx = tid + p * 256, row = idx >> 3;
    int ch = ((idx & 7) ^ (row & 7)) * 8;
    async_ld16(qbase + (size_t)(t0 + row) * 2304 + ch, Qs + (wave * 64 + p * 256) * 8);
  }
  float zacc[8];
#pragma unroll
  for (int j = 0; j < 8; ++j) zacc[j] = 0.f;

  for (int lt = 0; lt < 8; ++lt) {
#pragma unroll
    for (int p = 0; p < 4; ++p) {
      int idx = tid + p * 256, row = idx >> 3;
      int ch = ((idx & 7) ^ (row & 7)) * 8;
      async_ld16(kbase + (size_t)(lt * 128 + row) * 2304 + ch, Ks + (wave * 64 + p * 256) * 8);
    }
    __syncthreads();
    f32x4 acc[2][8];
#pragma unroll
    for (int i = 0; i < 2; ++i)
#pragma unroll
      for (int j = 0; j < 8; ++j) acc[i][j] = (f32x4){0.f, 0.f, 0.f, 0.f};
#pragma unroll
    for (int ks = 0; ks < 2; ++ks) {
      bf16x8 af[2], bf[8];
#pragma unroll
      for (int i = 0; i < 2; ++i) {
        int m = wave * 32 + i * 16 + lo;
        int slot = (ks * 4 + quad) ^ (m & 7);
        af[i] = *(const bf16x8*)(Ks + m * 64 + slot * 8);
      }
#pragma unroll
      for (int j = 0; j < 8; ++j) {
        int n = j * 16 + lo;
        int slot = (ks * 4 + quad) ^ (n & 7);
        bf[j] = *(const bf16x8*)(Qs + n * 64 + slot * 8);
      }
#pragma unroll
      for (int i = 0; i < 2; ++i)
#pragma unroll
        for (int j = 0; j < 8; ++j)
          acc[i][j] = __builtin_amdgcn_mfma_f32_16x16x32_bf16(af[i], bf[j], acc[i][j], 0, 0, 0);
    }
#pragma unroll
    for (int j = 0; j < 8; ++j)
#pragma unroll
      for (int i = 0; i < 2; ++i)
#pragma unroll
        for (int r = 0; r < 4; ++r)
          zacc[j] += __expf(acc[i][j][r] * 0.125f);
    __syncthreads();
  }
#pragma unroll
  for (int j = 0; j < 8; ++j) {
    float v = zacc[j];
    v += __shfl_xor(v, 16);
    v += __shfl_xor(v, 32);
    zacc[j] = v;
  }
  if (quad == 0)
#pragma unroll
    for (int j = 0; j < 8; ++j) zred[wave][j * 16 + lo] = zacc[j];
  __syncthreads();
  if (tid < 128) {
    float z = zred[0][tid] + zred[1][tid] + zred[2][tid] + zred[3][tid];
    zinv[(size_t)bh * 1024 + t0 + tid] = 1.0f / z;
  }
}

// --------------- fused attention output -------------------------------------
// out[l][c] = sum_t exp(0.125*K[l].Q[t]) * invZ[t] * V[t][c]
// grid (8 l-blocks, 96 bh). LDS: K-tile(16K) Q(8K) V(8K) E(16K) = 48 KB.
__global__ __launch_bounds__(256, 2) void attn_out(const u16* __restrict__ tb,
                                                   const u16* __restrict__ vt,
                                                   const float* __restrict__ zinv,
                                                   u16* __restrict__ ao) {
  int bh = blockIdx.y, b = bh / 12, h = bh % 12;
  int l0 = blockIdx.x * 128;
  __shared__ u16 Ks[128 * 64];
  __shared__ u16 Qs[64 * 64];
  __shared__ u16 Vs[64 * 64];
  __shared__ u16 Es[128 * 64];
  int tid = threadIdx.x, wave = tid >> 6, lane = tid & 63;
  int quad = lane >> 4, lo = lane & 15;
  const u16* qbase = tb + (size_t)(b * 1024) * 2304 + h * 64;
  const u16* kbase = qbase + 768;
  const u16* vbase = vt + (size_t)bh * 65536;
  const float* zf = zinv + (size_t)bh * 1024;

#pragma unroll
  for (int p = 0; p < 4; ++p) {
    int idx = tid + p * 256, row = idx >> 3;
    int ch = ((idx & 7) ^ (row & 7)) * 8;
    async_ld16(kbase + (size_t)(l0 + row) * 2304 + ch, Ks + (wave * 64 + p * 256) * 8);
  }
  f32x4 oacc[2][4];
#pragma unroll
  for (int i = 0; i < 2; ++i)
#pragma unroll
    for (int j = 0; j < 4; ++j) oacc[i][j] = (f32x4){0.f, 0.f, 0.f, 0.f};

  for (int tt = 0; tt < 16; ++tt) {
    int t0 = tt * 64;
#pragma unroll
    for (int p = 0; p < 2; ++p) {
      int idx = tid + p * 256, row = idx >> 3;
      int ch = ((idx & 7) ^ (row & 7)) * 8;
      async_ld16(qbase + (size_t)(t0 + row) * 2304 + ch, Qs + (wave * 64 + p * 256) * 8);
      async_ld16(vbase + (size_t)row * 1024 + t0 + ch, Vs + (wave * 64 + p * 256) * 8);
    }
    __syncthreads();
    // S-tile: 128 l x 64 t
    f32x4 sacc[2][4];
#pragma unroll
    for (int i = 0; i < 2; ++i)
#pragma unroll
      for (int j = 0; j < 4; ++j) sacc[i][j] = (f32x4){0.f, 0.f, 0.f, 0.f};
#pragma unroll
    for (int ks = 0; ks < 2; ++ks) {
      bf16x8 af[2], bq[4];
#pragma unroll
      for (int i = 0; i < 2; ++i) {
        int m = wave * 32 + i * 16 + lo;
        int slot = (ks * 4 + quad) ^ (m & 7);
        af[i] = *(const bf16x8*)(Ks + m * 64 + slot * 8);
      }
#pragma unroll
      for (int j = 0; j < 4; ++j) {
        int n = j * 16 + lo;
        int slot = (ks * 4 + quad) ^ (n & 7);
        bq[j] = *(const bf16x8*)(Qs + n * 64 + slot * 8);
      }
#pragma unroll
      for (int i = 0; i < 2; ++i)
#pragma unroll
        for (int j = 0; j < 4; ++j)
          sacc[i][j] = __builtin_amdgcn_mfma_f32_16x16x32_bf16(af[i], bq[j], sacc[i][j], 0, 0, 0);
    }
    // E = exp(S)*invZ -> Es (rows are wave-local: no barrier needed)
#pragma unroll
    for (int j = 0; j < 4; ++j) {
      int t_loc = j * 16 + lo;
      float zi = zf[t0 + t_loc];
      int ch = t_loc >> 3, pos = t_loc & 7;
#pragma unroll
      for (int i = 0; i < 2; ++i)
#pragma unroll
        for (int r = 0; r < 4; ++r) {
          int l_loc = wave * 32 + i * 16 + quad * 4 + r;
          float e = __expf(sacc[i][j][r] * 0.125f) * zi;
          Es[l_loc * 64 + ((ch ^ (l_loc & 7)) * 8 + pos)] = f2bf(e);
        }
    }
    // out += E(128x64) @ V^T(64t x 64c)
#pragma unroll
    for (int ks = 0; ks < 2; ++ks) {
      bf16x8 ae[2], bv[4];
#pragma unroll
      for (int i = 0; i < 2; ++i) {
        int m = wave * 32 + i * 16 + lo;
        int slot = (ks * 4 + quad) ^ (m & 7);
        ae[i] = *(const bf16x8*)(Es + m * 64 + slot * 8);
      }
#pragma unroll
      for (int j = 0; j < 4; ++j) {
        int n = j * 16 + lo;
        int slot = (ks * 4 + quad) ^ (n & 7);
        bv[j] = *(const bf16x8*)(Vs + n * 64 + slot * 8);
      }
#pragma unroll
      for (int i = 0; i < 2; ++i)
#pragma unroll
        for (int j = 0; j < 4; ++j)
          oacc[i][j] = __builtin_amdgcn_mfma_f32_16x16x32_bf16(ae[i], bv[j], oacc[i][j], 0, 0, 0);
    }
    __syncthreads();
  }
#pragma unroll
  for (int j = 0; j < 4; ++j) {
    int c = j * 16 + lo;
#pragma unroll
    for (int i = 0; i < 2; ++i)
#pragma unroll
      for (int r = 0; r < 4; ++r) {
        int l = l0 + wave * 32 + i * 16 + quad * 4 + r;
        ao[(size_t)(b * 1024 + l) * 768 + h * 64 + c] = f2bf(oacc[i][j][r]);
      }
  }
}

// ----------------------------- host orchestration ---------------------------
static void run_block(hipStream_t stream, const void* inp, int inF32,
                      const float* g, const float* be,
                      const float* W1, const float* b1, const float* W2, const float* b2,
                      int N2, void* outp, int outF32,
                      u16* xn, u16* hS, u16* wt1, u16* wt2) {
  transpose_f32_bf16<<<dim3(3072 / 32, 768 / 32), dim3(32, 8), 0, stream>>>(W1, wt1, 768, 3072);
  transpose_f32_bf16<<<dim3(N2 / 32, 3072 / 32), dim3(32, 8), 0, stream>>>(W2, wt2, 3072, N2);
  ln_kernel<<<8192, 256, 0, stream>>>(inp, g, be, xn, inF32);
  gemm_mfma<<<dim3(3072 / 128, 8192 / 128), dim3(256), 0, stream>>>(
      xn, 768, wt1, 768, hS, 3072, 8192, 3072, 768, b1, 1, 0);
  gemm_mfma<<<dim3(N2 / 128, 8192 / 128), dim3(256), 0, stream>>>(
      hS, 3072, wt2, 3072, outp, N2, 8192, N2, 3072, b2, 0, outF32);
}

extern "C" void kernel_launch(void* const* d_in, const int* in_sizes, int n_in,
                              void* d_out, int out_size, void* d_ws, size_t ws_size,
                              hipStream_t stream) {
  const float* x       = (const float*)d_in[0];
  const float* qkv_g   = (const float*)d_in[1];
  const float* qkv_b   = (const float*)d_in[2];
  const float* qkv_W1  = (const float*)d_in[3];
  const float* qkv_b1  = (const float*)d_in[4];
  const float* qkv_W2  = (const float*)d_in[5];
  const float* qkv_b2  = (const float*)d_in[6];
  const float* proj_g  = (const float*)d_in[7];
  const float* proj_b  = (const float*)d_in[8];
  const float* proj_W1 = (const float*)d_in[9];
  const float* proj_b1 = (const float*)d_in[10];
  const float* proj_W2 = (const float*)d_in[11];
  const float* proj_b2 = (const float*)d_in[12];
  const float* mlp_g   = (const float*)d_in[13];
  const float* mlp_b   = (const float*)d_in[14];
  const float* mlp_W1  = (const float*)d_in[15];
  const float* mlp_b1  = (const float*)d_in[16];
  const float* mlp_W2  = (const float*)d_in[17];
  const float* mlp_b2  = (const float*)d_in[18];

  u16* ws  = (u16*)d_ws;               // u16 offsets; footprint identical to R1
  u16* xn  = ws;                       // 6291456 (LN out; zinv aliases this)
  u16* tb  = ws + 6291456;             // qkv out 8192x2304
  u16* ao  = ws + 25165824;            // attention out
  u16* yb  = ws + 31457280;            // proj block out
  u16* vt  = ws + 37748736;            // V^T [96][64][1024]
  u16* wt1 = ws + 44040192;            // W1^T bf16
  u16* wt2 = ws + 46399488;            // W2^T bf16
  u16* hS  = ws + 53477376;            // hidden 8192x3072
  float* zinv = (float*)xn;            // 96*1024 floats, aliases dead xn

  // ---- qkv block ----
  run_block(stream, x, 1, qkv_g, qkv_b, qkv_W1, qkv_b1, qkv_W2, qkv_b2, 2304,
            tb, 0, xn, hS, wt1, wt2);

  // ---- attention (fused) ----
  vtrans<<<dim3(32, 2, 96), dim3(32, 8), 0, stream>>>(tb, vt);
  zstats<<<dim3(8, 96), dim3(256), 0, stream>>>(tb, zinv);
  attn_out<<<dim3(8, 96), dim3(256), 0, stream>>>(tb, vt, zinv, ao);

  // ---- proj block ----
  run_block(stream, ao, 0, proj_g, proj_b, proj_W1, proj_b1, proj_W2, proj_b2, 768,
            yb, 0, xn, hS, wt1, wt2);
  // ---- mlp block ----
  run_block(stream, yb, 0, mlp_g, mlp_b, mlp_W1, mlp_b1, mlp_W2, mlp_b2, 768,
            d_out, 1, xn, hS, wt1, wt2);
}

// Round 4
// 706.567 us; speedup vs baseline: 2.3283x; 1.0375x over previous
//
#include <hip/hip_runtime.h>
#include <stdint.h>

// ---------------------------------------------------------------------------
// TransformerBlock: 3x (LN -> FC(768,3072) -> GELU -> FC(3072,N)) + attention.
// fp32 in/out, bf16 MFMA compute with fp32 acc.
// Round-4 changes:
//  (1) XCD row-banded tile swizzle in gemm_mfma: XCD x (lin%8) owns row-tile
//      band [x*gy/8, (x+1)*gy/8) -> per-XCD L2 k-slice working set ~400 KB
//      (fits 4 MB L2), cutting 5x A/B over-fetch (340 MB -> ~180 MB).
//  (2) Split-K=2 for the N=768 FC2 GEMMs (grid 384->768 blocks, fixes the
//      1.5-block/CU occupancy tail). fp32 partials land in the dead tb+ao ws
//      region; combine fused into next LN (proj) or a tiny add2 (mlp/final).
// ---------------------------------------------------------------------------

typedef unsigned short u16;
typedef __attribute__((ext_vector_type(8))) short bf16x8;
typedef __attribute__((ext_vector_type(4))) float f32x4;
typedef __attribute__((address_space(1))) unsigned int as1_u32;
typedef __attribute__((address_space(3))) unsigned int as3_u32;

#define PHALF 6291456  // fp32 elements per split-K partial buffer (8192*768)

__device__ __forceinline__ float bf2f(u16 u) {
  union { unsigned int i; float f; } v; v.i = ((unsigned int)u) << 16; return v.f;
}
__device__ __forceinline__ u16 f2bf(float f) {
  union { float f; unsigned int i; } v; v.f = f;
  unsigned int r = v.i + 0x7fffu + ((v.i >> 16) & 1u);  // RNE
  return (u16)(r >> 16);
}
__device__ __forceinline__ float gelu_exact(float x) {
  return 0.5f * x * (1.0f + erff(x * 0.70710678118654752f));
}
__device__ __forceinline__ void async_ld16(const u16* g, u16* l) {
  __builtin_amdgcn_global_load_lds((const as1_u32*)g, (as3_u32*)l, 16, 0, 0);
}

// ------------------- LayerNorm (per token, C=768) -> bf16 -------------------
// inMode: 0 = bf16 rows, 1 = fp32 rows, 2 = sum of two fp32 partial buffers.
__global__ __launch_bounds__(256) void ln_kernel(const void* __restrict__ xv,
                                                 const float* __restrict__ g,
                                                 const float* __restrict__ be,
                                                 u16* __restrict__ out, int inMode) {
  int token = blockIdx.x, tid = threadIdx.x;
  int wave = tid >> 6, lane = tid & 63;
  float v0, v1, v2;
  if (inMode == 1) {
    const float* row = (const float*)xv + (size_t)token * 768;
    v0 = row[tid]; v1 = row[tid + 256]; v2 = row[tid + 512];
  } else if (inMode == 2) {
    const float* row = (const float*)xv + (size_t)token * 768;
    const float* row2 = row + PHALF;
    v0 = row[tid] + row2[tid];
    v1 = row[tid + 256] + row2[tid + 256];
    v2 = row[tid + 512] + row2[tid + 512];
  } else {
    const u16* row = (const u16*)xv + (size_t)token * 768;
    v0 = bf2f(row[tid]); v1 = bf2f(row[tid + 256]); v2 = bf2f(row[tid + 512]);
  }
  float s = v0 + v1 + v2;
  float q = v0 * v0 + v1 * v1 + v2 * v2;
#pragma unroll
  for (int m = 1; m < 64; m <<= 1) { s += __shfl_xor(s, m); q += __shfl_xor(q, m); }
  __shared__ float red[8];
  if (lane == 0) { red[wave] = s; red[4 + wave] = q; }
  __syncthreads();
  s = red[0] + red[1] + red[2] + red[3];
  q = red[4] + red[5] + red[6] + red[7];
  float mean = s * (1.0f / 768.0f);
  float var  = q * (1.0f / 768.0f) - mean * mean;
  float inv  = rsqrtf(var + 1e-5f);
  u16* o = out + (size_t)token * 768;
  o[tid]       = f2bf((v0 - mean) * inv * g[tid]       + be[tid]);
  o[tid + 256] = f2bf((v1 - mean) * inv * g[tid + 256] + be[tid + 256]);
  o[tid + 512] = f2bf((v2 - mean) * inv * g[tid + 512] + be[tid + 512]);
}

// ------------- fp32 (R x C) -> bf16 transposed (C x R) ----------------------
__global__ __launch_bounds__(256) void transpose_f32_bf16(const float* __restrict__ in,
                                                          u16* __restrict__ out,
                                                          int R, int Cc) {
  __shared__ u16 tile[32][33];
  int c0 = blockIdx.x * 32, r0 = blockIdx.y * 32;
  int tx = threadIdx.x, ty = threadIdx.y;  // 32 x 8
  for (int i = ty; i < 32; i += 8)
    tile[i][tx] = f2bf(in[(size_t)(r0 + i) * Cc + c0 + tx]);
  __syncthreads();
  for (int i = ty; i < 32; i += 8)
    out[(size_t)(c0 + i) * R + r0 + tx] = tile[tx][i];
}

// ------------- V transpose: t(token, 1536 + h*64 + c) -> vt[bh][c][t] -------
__global__ __launch_bounds__(256) void vtrans(const u16* __restrict__ t,
                                              u16* __restrict__ vt) {
  int bh = blockIdx.z, b = bh / 12, h = bh % 12;
  int t0 = blockIdx.x * 32, c0 = blockIdx.y * 32;
  __shared__ u16 tile[32][33];
  int tx = threadIdx.x, ty = threadIdx.y;
  for (int i = ty; i < 32; i += 8)
    tile[i][tx] = t[(size_t)(b * 1024 + t0 + i) * 2304 + 1536 + h * 64 + c0 + tx];
  __syncthreads();
  for (int i = ty; i < 32; i += 8)
    vt[(size_t)bh * 65536 + (size_t)(c0 + i) * 1024 + t0 + tx] = tile[tx][i];
}

// -------------------- add2: out = P0 + P1 (split-K combine) -----------------
__global__ __launch_bounds__(256) void add2_kernel(const float* __restrict__ P,
                                                   float* __restrict__ out) {
  int idx = blockIdx.x * 256 + threadIdx.x;   // f32x4 index, n/4 = 1572864
  const f32x4* p0 = (const f32x4*)P;
  const f32x4* p1 = (const f32x4*)(P + PHALF);
  ((f32x4*)out)[idx] = p0[idx] + p1[idx];
}

// ----------------------------- MFMA GEMM (FC layers) ------------------------
// kSplit = K handled per z-slice (kOff = z*kSplit). cF32: fp32 C (partials at
// z*cZStride). Bias applied only on z==0. XCD row-band swizzle when gy%8==0.
#define BM 128
#define BN 128
#define BKK 64

__global__ __launch_bounds__(256, 4) void gemm_mfma(
    const u16* __restrict__ A, int lda,
    const u16* __restrict__ B, int ldb,
    void* __restrict__ C, int ldc,
    int M, int N, int kSplit,
    const float* __restrict__ bias, int act, int cF32, long long cZStride) {
  __shared__ u16 As[BM * BKK];
  __shared__ u16 Bs[BN * BKK];
  // XCD row-banded tile mapping: lin%8 = XCD (round-robin dispatch); XCD x
  // owns row band [x*gy/8, (x+1)*gy/8), col-fastest within band.
  int gx = gridDim.x, gy = gridDim.y;
  int bx, by;
  if ((gy & 7) == 0) {
    int lin = blockIdx.y * gx + blockIdx.x;
    int xcd = lin & 7, s = lin >> 3;
    int r = s / gx;
    by = xcd * (gy >> 3) + r;
    bx = s - r * gx;
  } else { bx = blockIdx.x; by = blockIdx.y; }
  int m0 = by * BM, n0 = bx * BN;
  int kOff = blockIdx.z * kSplit;
  int tid = threadIdx.x;
  int wave = tid >> 6, lane = tid & 63;
  int quad = lane >> 4, lo = lane & 15;
  int wr = (wave >> 1) * 64, wc = (wave & 1) * 64;

  f32x4 acc[4][4];
#pragma unroll
  for (int i = 0; i < 4; ++i)
#pragma unroll
    for (int j = 0; j < 4; ++j) acc[i][j] = (f32x4){0.f, 0.f, 0.f, 0.f};

  for (int k0 = kOff; k0 < kOff + kSplit; k0 += BKK) {
    // XOR-swizzled staging: lane(row,slot) fetches global chunk slot^(row&7)
#pragma unroll
    for (int p = 0; p < 4; ++p) {
      int idx = tid + p * 256;
      int row = idx >> 3;
      int gch = ((idx & 7) ^ (row & 7)) * 8;
      int ldsOff = (wave * 64 + p * 256) * 8;
      async_ld16(A + (long long)(m0 + row) * lda + k0 + gch, As + ldsOff);
      async_ld16(B + (long long)(n0 + row) * ldb + k0 + gch, Bs + ldsOff);
    }
    __syncthreads();
#pragma unroll
    for (int ks = 0; ks < 2; ++ks) {
      bf16x8 af[4], bf[4];
#pragma unroll
      for (int i = 0; i < 4; ++i) {
        int m = wr + i * 16 + lo;
        int slot = (ks * 4 + quad) ^ (m & 7);
        af[i] = *(const bf16x8*)(As + m * BKK + slot * 8);
      }
#pragma unroll
      for (int j = 0; j < 4; ++j) {
        int n = wc + j * 16 + lo;
        int slot = (ks * 4 + quad) ^ (n & 7);
        bf[j] = *(const bf16x8*)(Bs + n * BKK + slot * 8);
      }
#pragma unroll
      for (int i = 0; i < 4; ++i)
#pragma unroll
        for (int j = 0; j < 4; ++j)
          acc[i][j] = __builtin_amdgcn_mfma_f32_16x16x32_bf16(af[i], bf[j], acc[i][j], 0, 0, 0);
    }
    __syncthreads();
  }

  // C/D layout: col = lane&15, row = quad*4+reg.
  long long cZ = (long long)blockIdx.z * cZStride;
#pragma unroll
  for (int j = 0; j < 4; ++j) {
    int col = n0 + wc + j * 16 + lo;
    float bv = (bias && blockIdx.z == 0) ? bias[col] : 0.0f;
#pragma unroll
    for (int i = 0; i < 4; ++i) {
      int rb = m0 + wr + i * 16 + quad * 4;
#pragma unroll
      for (int r = 0; r < 4; ++r) {
        int row = rb + r;
        float v = acc[i][j][r] + bv;
        if (act) v = gelu_exact(v);
        long long ci = cZ + (long long)row * ldc + col;
        if (cF32) ((float*)C)[ci] = v;
        else      ((u16*)C)[ci] = f2bf(v);
      }
    }
  }
}

// --------------- zstats: invZ[t] = 1 / sum_l exp(0.125*K[l].Q[t]) -----------
// grid (8 t-blocks, 96 bh), block 256. tb holds qkv output rows of 2304.
__global__ __launch_bounds__(256, 2) void zstats(const u16* __restrict__ tb,
                                                 float* __restrict__ zinv) {
  int bh = blockIdx.y, b = bh / 12, h = bh % 12;
  int t0 = blockIdx.x * 128;
  __shared__ u16 Qs[128 * 64];
  __shared__ u16 Ks[128 * 64];
  __shared__ float zred[4][128];
  int tid = threadIdx.x, wave = tid >> 6, lane = tid & 63;
  int quad = lane >> 4, lo = lane & 15;
  const u16* qbase = tb + (size_t)(b * 1024) * 2304 + h * 64;
  const u16* kbase = qbase + 768;

#pragma unroll
  for (int p = 0; p < 4; ++p) {
    int idx = tid + p * 256, row = idx >> 3;
    int ch = ((idx & 7) ^ (row & 7)) * 8;
    async_ld16(qbase + (size_t)(t0 + row) * 2304 + ch, Qs + (wave * 64 + p * 256) * 8);
  }
  float zacc[8];
#pragma unroll
  for (int j = 0; j < 8; ++j) zacc[j] = 0.f;

  for (int lt = 0; lt < 8; ++lt) {
#pragma unroll
    for (int p = 0; p < 4; ++p) {
      int idx = tid + p * 256, row = idx >> 3;
      int ch = ((idx & 7) ^ (row & 7)) * 8;
      async_ld16(kbase + (size_t)(lt * 128 + row) * 2304 + ch, Ks + (wave * 64 + p * 256) * 8);
    }
    __syncthreads();
    f32x4 acc[2][8];
#pragma unroll
    for (int i = 0; i < 2; ++i)
#pragma unroll
      for (int j = 0; j < 8; ++j) acc[i][j] = (f32x4){0.f, 0.f, 0.f, 0.f};
#pragma unroll
    for (int ks = 0; ks < 2; ++ks) {
      bf16x8 af[2], bf[8];
#pragma unroll
      for (int i = 0; i < 2; ++i) {
        int m = wave * 32 + i * 16 + lo;
        int slot = (ks * 4 + quad) ^ (m & 7);
        af[i] = *(const bf16x8*)(Ks + m * 64 + slot * 8);
      }
#pragma unroll
      for (int j = 0; j < 8; ++j) {
        int n = j * 16 + lo;
        int slot = (ks * 4 + quad) ^ (n & 7);
        bf[j] = *(const bf16x8*)(Qs + n * 64 + slot * 8);
      }
#pragma unroll
      for (int i = 0; i < 2; ++i)
#pragma unroll
        for (int j = 0; j < 8; ++j)
          acc[i][j] = __builtin_amdgcn_mfma_f32_16x16x32_bf16(af[i], bf[j], acc[i][j], 0, 0, 0);
    }
#pragma unroll
    for (int j = 0; j < 8; ++j)
#pragma unroll
      for (int i = 0; i < 2; ++i)
#pragma unroll
        for (int r = 0; r < 4; ++r)
          zacc[j] += __expf(acc[i][j][r] * 0.125f);
    __syncthreads();
  }
#pragma unroll
  for (int j = 0; j < 8; ++j) {
    float v = zacc[j];
    v += __shfl_xor(v, 16);
    v += __shfl_xor(v, 32);
    zacc[j] = v;
  }
  if (quad == 0)
#pragma unroll
    for (int j = 0; j < 8; ++j) zred[wave][j * 16 + lo] = zacc[j];
  __syncthreads();
  if (tid < 128) {
    float z = zred[0][tid] + zred[1][tid] + zred[2][tid] + zred[3][tid];
    zinv[(size_t)bh * 1024 + t0 + tid] = 1.0f / z;
  }
}

// --------------- fused attention output -------------------------------------
// out[l][c] = sum_t exp(0.125*K[l].Q[t]) * invZ[t] * V[t][c]
// grid (8 l-blocks, 96 bh). LDS: K-tile(16K) Q(8K) V(8K) E(16K) = 48 KB.
__global__ __launch_bounds__(256, 2) void attn_out(const u16* __restrict__ tb,
                                                   const u16* __restrict__ vt,
                                                   const float* __restrict__ zinv,
                                                   u16* __restrict__ ao) {
  int bh = blockIdx.y, b = bh / 12, h = bh % 12;
  int l0 = blockIdx.x * 128;
  __shared__ u16 Ks[128 * 64];
  __shared__ u16 Qs[64 * 64];
  __shared__ u16 Vs[64 * 64];
  __shared__ u16 Es[128 * 64];
  int tid = threadIdx.x, wave = tid >> 6, lane = tid & 63;
  int quad = lane >> 4, lo = lane & 15;
  const u16* qbase = tb + (size_t)(b * 1024) * 2304 + h * 64;
  const u16* kbase = qbase + 768;
  const u16* vbase = vt + (size_t)bh * 65536;
  const float* zf = zinv + (size_t)bh * 1024;

#pragma unroll
  for (int p = 0; p < 4; ++p) {
    int idx = tid + p * 256, row = idx >> 3;
    int ch = ((idx & 7) ^ (row & 7)) * 8;
    async_ld16(kbase + (size_t)(l0 + row) * 2304 + ch, Ks + (wave * 64 + p * 256) * 8);
  }
  f32x4 oacc[2][4];
#pragma unroll
  for (int i = 0; i < 2; ++i)
#pragma unroll
    for (int j = 0; j < 4; ++j) oacc[i][j] = (f32x4){0.f, 0.f, 0.f, 0.f};

  for (int tt = 0; tt < 16; ++tt) {
    int t0 = tt * 64;
#pragma unroll
    for (int p = 0; p < 2; ++p) {
      int idx = tid + p * 256, row = idx >> 3;
      int ch = ((idx & 7) ^ (row & 7)) * 8;
      async_ld16(qbase + (size_t)(t0 + row) * 2304 + ch, Qs + (wave * 64 + p * 256) * 8);
      async_ld16(vbase + (size_t)row * 1024 + t0 + ch, Vs + (wave * 64 + p * 256) * 8);
    }
    __syncthreads();
    // S-tile: 128 l x 64 t
    f32x4 sacc[2][4];
#pragma unroll
    for (int i = 0; i < 2; ++i)
#pragma unroll
      for (int j = 0; j < 4; ++j) sacc[i][j] = (f32x4){0.f, 0.f, 0.f, 0.f};
#pragma unroll
    for (int ks = 0; ks < 2; ++ks) {
      bf16x8 af[2], bq[4];
#pragma unroll
      for (int i = 0; i < 2; ++i) {
        int m = wave * 32 + i * 16 + lo;
        int slot = (ks * 4 + quad) ^ (m & 7);
        af[i] = *(const bf16x8*)(Ks + m * 64 + slot * 8);
      }
#pragma unroll
      for (int j = 0; j < 4; ++j) {
        int n = j * 16 + lo;
        int slot = (ks * 4 + quad) ^ (n & 7);
        bq[j] = *(const bf16x8*)(Qs + n * 64 + slot * 8);
      }
#pragma unroll
      for (int i = 0; i < 2; ++i)
#pragma unroll
        for (int j = 0; j < 4; ++j)
          sacc[i][j] = __builtin_amdgcn_mfma_f32_16x16x32_bf16(af[i], bq[j], sacc[i][j], 0, 0, 0);
    }
    // E = exp(S)*invZ -> Es (rows are wave-local: no barrier needed)
#pragma unroll
    for (int j = 0; j < 4; ++j) {
      int t_loc = j * 16 + lo;
      float zi = zf[t0 + t_loc];
      int ch = t_loc >> 3, pos = t_loc & 7;
#pragma unroll
      for (int i = 0; i < 2; ++i)
#pragma unroll
        for (int r = 0; r < 4; ++r) {
          int l_loc = wave * 32 + i * 16 + quad * 4 + r;
          float e = __expf(sacc[i][j][r] * 0.125f) * zi;
          Es[l_loc * 64 + ((ch ^ (l_loc & 7)) * 8 + pos)] = f2bf(e);
        }
    }
    // out += E(128x64) @ V^T(64t x 64c)
#pragma unroll
    for (int ks = 0; ks < 2; ++ks) {
      bf16x8 ae[2], bv[4];
#pragma unroll
      for (int i = 0; i < 2; ++i) {
        int m = wave * 32 + i * 16 + lo;
        int slot = (ks * 4 + quad) ^ (m & 7);
        ae[i] = *(const bf16x8*)(Es + m * 64 + slot * 8);
      }
#pragma unroll
      for (int j = 0; j < 4; ++j) {
        int n = j * 16 + lo;
        int slot = (ks * 4 + quad) ^ (n & 7);
        bv[j] = *(const bf16x8*)(Vs + n * 64 + slot * 8);
      }
#pragma unroll
      for (int i = 0; i < 2; ++i)
#pragma unroll
        for (int j = 0; j < 4; ++j)
          oacc[i][j] = __builtin_amdgcn_mfma_f32_16x16x32_bf16(ae[i], bv[j], oacc[i][j], 0, 0, 0);
    }
    __syncthreads();
  }
#pragma unroll
  for (int j = 0; j < 4; ++j) {
    int c = j * 16 + lo;
#pragma unroll
    for (int i = 0; i < 2; ++i)
#pragma unroll
      for (int r = 0; r < 4; ++r) {
        int l = l0 + wave * 32 + i * 16 + quad * 4 + r;
        ao[(size_t)(b * 1024 + l) * 768 + h * 64 + c] = f2bf(oacc[i][j][r]);
      }
  }
}

// ----------------------------- host orchestration ---------------------------
extern "C" void kernel_launch(void* const* d_in, const int* in_sizes, int n_in,
                              void* d_out, int out_size, void* d_ws, size_t ws_size,
                              hipStream_t stream) {
  const float* x       = (const float*)d_in[0];
  const float* qkv_g   = (const float*)d_in[1];
  const float* qkv_b   = (const float*)d_in[2];
  const float* qkv_W1  = (const float*)d_in[3];
  const float* qkv_b1  = (const float*)d_in[4];
  const float* qkv_W2  = (const float*)d_in[5];
  const float* qkv_b2  = (const float*)d_in[6];
  const float* proj_g  = (const float*)d_in[7];
  const float* proj_b  = (const float*)d_in[8];
  const float* proj_W1 = (const float*)d_in[9];
  const float* proj_b1 = (const float*)d_in[10];
  const float* proj_W2 = (const float*)d_in[11];
  const float* proj_b2 = (const float*)d_in[12];
  const float* mlp_g   = (const float*)d_in[13];
  const float* mlp_b   = (const float*)d_in[14];
  const float* mlp_W1  = (const float*)d_in[15];
  const float* mlp_b1  = (const float*)d_in[16];
  const float* mlp_W2  = (const float*)d_in[17];
  const float* mlp_b2  = (const float*)d_in[18];

  u16* ws  = (u16*)d_ws;               // u16 offsets; ~157 MB total
  u16* xn  = ws;                       // 6291456 (LN out; zinv aliases this)
  u16* tb  = ws + 6291456;             // qkv out 8192x2304
  u16* ao  = ws + 25165824;            // attention out
  u16* yb  = ws + 31457280;            // proj block out
  u16* vt  = ws + 37748736;            // V^T [96][64][1024]
  u16* wt1 = ws + 44040192;            // W1^T bf16
  u16* wt2 = ws + 46399488;            // W2^T bf16
  u16* hS  = ws + 53477376;            // hidden 8192x3072
  float* zinv = (float*)xn;            // 96*1024 floats, aliases dead xn
  float* Pf  = (float*)tb;             // split-K partials 2x8192x768 fp32,
                                       // aliases dead tb+ao (50.3 MB exactly)

  // ---- qkv block ----
  transpose_f32_bf16<<<dim3(96, 24), dim3(32, 8), 0, stream>>>(qkv_W1, wt1, 768, 3072);
  transpose_f32_bf16<<<dim3(72, 96), dim3(32, 8), 0, stream>>>(qkv_W2, wt2, 3072, 2304);
  ln_kernel<<<8192, 256, 0, stream>>>(x, qkv_g, qkv_b, xn, 1);
  gemm_mfma<<<dim3(24, 64), dim3(256), 0, stream>>>(
      xn, 768, wt1, 768, hS, 3072, 8192, 3072, 768, qkv_b1, 1, 0, 0);
  gemm_mfma<<<dim3(18, 64), dim3(256), 0, stream>>>(
      hS, 3072, wt2, 3072, tb, 2304, 8192, 2304, 3072, qkv_b2, 0, 0, 0);

  // ---- attention (fused) ----
  vtrans<<<dim3(32, 2, 96), dim3(32, 8), 0, stream>>>(tb, vt);
  zstats<<<dim3(8, 96), dim3(256), 0, stream>>>(tb, zinv);
  attn_out<<<dim3(8, 96), dim3(256), 0, stream>>>(tb, vt, zinv, ao);

  // ---- proj block ----
  transpose_f32_bf16<<<dim3(96, 24), dim3(32, 8), 0, stream>>>(proj_W1, wt1, 768, 3072);
  transpose_f32_bf16<<<dim3(24, 96), dim3(32, 8), 0, stream>>>(proj_W2, wt2, 3072, 768);
  ln_kernel<<<8192, 256, 0, stream>>>(ao, proj_g, proj_b, xn, 0);
  gemm_mfma<<<dim3(24, 64), dim3(256), 0, stream>>>(
      xn, 768, wt1, 768, hS, 3072, 8192, 3072, 768, proj_b1, 1, 0, 0);
  // split-K=2: z in {0,1}, each 1536; fp32 partials (tb/ao dead here)
  gemm_mfma<<<dim3(6, 64, 2), dim3(256), 0, stream>>>(
      hS, 3072, wt2, 3072, Pf, 768, 8192, 768, 1536, proj_b2, 0, 1, PHALF);

  // ---- mlp block ----
  transpose_f32_bf16<<<dim3(96, 24), dim3(32, 8), 0, stream>>>(mlp_W1, wt1, 768, 3072);
  transpose_f32_bf16<<<dim3(24, 96), dim3(32, 8), 0, stream>>>(mlp_W2, wt2, 3072, 768);
  ln_kernel<<<8192, 256, 0, stream>>>(Pf, mlp_g, mlp_b, xn, 2);  // combines P0+P1
  gemm_mfma<<<dim3(24, 64), dim3(256), 0, stream>>>(
      xn, 768, wt1, 768, hS, 3072, 8192, 3072, 768, mlp_b1, 1, 0, 0);
  gemm_mfma<<<dim3(6, 64, 2), dim3(256), 0, stream>>>(
      hS, 3072, wt2, 3072, Pf, 768, 8192, 768, 1536, mlp_b2, 0, 1, PHALF);
  add2_kernel<<<6144, 256, 0, stream>>>(Pf, (float*)d_out);
}